// Round 1
// baseline (545.633 us; speedup 1.0000x reference)
//
#include <hip/hip_runtime.h>
#include <hip/hip_bf16.h>
#include <stdint.h>

typedef unsigned short u16;
typedef unsigned int u32;
typedef __bf16 bf16x8 __attribute__((ext_vector_type(8)));
typedef float f32x4 __attribute__((ext_vector_type(4)));
typedef u16 u16x8 __attribute__((ext_vector_type(8)));

#define S_LEN 2048
#define DMODEL 4096
#define NHEADS 32
#define NKVH 8
#define DHEAD 128

__device__ __forceinline__ float bf2f(u16 x) {
    union { u32 i; float f; } u; u.i = ((u32)x) << 16; return u.f;
}
__device__ __forceinline__ u16 f2bf(float f) {
    union { float f; u32 i; } u; u.f = f;
    u32 x = u.i;
    return (u16)((x + 0x7fffu + ((x >> 16) & 1u)) >> 16);
}
__device__ __forceinline__ bf16x8 ld_bf8(const void* p) {
    int4 v = *(const int4*)p;
    return __builtin_bit_cast(bf16x8, v);
}

// ---------------- fp32 -> bf16 elementwise ----------------
__global__ void k_cvt(const float* __restrict__ in, u16* __restrict__ out, int n8) {
    int i = blockIdx.x * 256 + threadIdx.x;
    if (i >= n8) return;
    const float4* p = (const float4*)in + (size_t)i * 2;
    float4 a = p[0], b = p[1];
    u16x8 o;
    o[0]=f2bf(a.x); o[1]=f2bf(a.y); o[2]=f2bf(a.z); o[3]=f2bf(a.w);
    o[4]=f2bf(b.x); o[5]=f2bf(b.y); o[6]=f2bf(b.z); o[7]=f2bf(b.w);
    *((u16x8*)out + i) = o;
}

// ---------------- transpose (+convert) to bf16: in[R][C] (ldin) -> out[C][R] ----------------
template<typename TIN>
__global__ void k_transpose_bf16(const TIN* __restrict__ in, u16* __restrict__ out,
                                 int R, int C, int ldin) {
    __shared__ u16 tile[32][33];
    int c0 = blockIdx.x * 32, r0 = blockIdx.y * 32;
    int tx = threadIdx.x & 31, ty = threadIdx.x >> 5;
    #pragma unroll
    for (int i = 0; i < 4; i++) {
        int r = ty + i * 8;
        TIN v = in[(size_t)(r0 + r) * ldin + c0 + tx];
        if constexpr (sizeof(TIN) == 4) tile[r][tx] = f2bf((float)v);
        else tile[r][tx] = (u16)v;
    }
    __syncthreads();
    #pragma unroll
    for (int i = 0; i < 4; i++) {
        int r = ty + i * 8;
        out[(size_t)(c0 + r) * R + r0 + tx] = tile[tx][r];
    }
}

// ---------------- RoPE in place on [S][nh*128] bf16 (row stride ld) ----------------
__global__ void k_rope(u16* __restrict__ X, const float* __restrict__ cosT,
                       const float* __restrict__ sinT, int nh, int ld) {
    int idx = blockIdx.x * 256 + threadIdx.x;
    int d = idx & 63;
    int h = (idx >> 6) % nh;
    int s = idx / (64 * nh);
    u16* p = X + (size_t)s * ld + h * DHEAD;
    float x1 = bf2f(p[d]), x2 = bf2f(p[d + 64]);
    float c1 = cosT[s * DHEAD + d],      s1 = sinT[s * DHEAD + d];
    float c2 = cosT[s * DHEAD + d + 64], s2 = sinT[s * DHEAD + d + 64];
    p[d]      = f2bf(x1 * c1 - x2 * s1);
    p[d + 64] = f2bf(x2 * c2 + x1 * s2);
}

// ---------------- m97-structure bt-GEMM: C[M][N] = A[M][K] * Bt[N][K]^T ----------------
typedef const __attribute__((address_space(1))) u32 GBUF;
typedef __attribute__((address_space(3))) u32 LBUF;

template<typename OUT_T>
__global__ __launch_bounds__(256)
void k_gemm_bt(const u16* __restrict__ A, const u16* __restrict__ Bt,
               OUT_T* __restrict__ C, int M, int N, int K) {
    __shared__ __align__(16) u16 As[128 * 32];
    __shared__ __align__(16) u16 Bs[128 * 32];
    const int m0 = blockIdx.y * 128, n0 = blockIdx.x * 128;
    const int tid = threadIdx.x, lane = tid & 63, wid = tid >> 6;
    const int wr = wid >> 1, wc = wid & 1;
    const int g = lane >> 4, lr = lane & 15;

    f32x4 acc[4][4] = {};

    for (int k0 = 0; k0 < K; k0 += 32) {
        __syncthreads();
        #pragma unroll
        for (int j = 0; j < 2; j++) {
            int c = wid * 128 + j * 64 + lane;     // chunk 0..511 (16B each)
            int r = c >> 2, co = (c & 3) << 3;     // row 0..127, col offset {0,8,16,24}
            __builtin_amdgcn_global_load_lds((GBUF*)(A  + (size_t)(m0 + r) * K + k0 + co),
                                             (LBUF*)(As + (size_t)(wid * 128 + j * 64) * 8), 16, 0, 0);
            __builtin_amdgcn_global_load_lds((GBUF*)(Bt + (size_t)(n0 + r) * K + k0 + co),
                                             (LBUF*)(Bs + (size_t)(wid * 128 + j * 64) * 8), 16, 0, 0);
        }
        __syncthreads();
        bf16x8 af[4], bf[4];
        #pragma unroll
        for (int i = 0; i < 4; i++)
            af[i] = ld_bf8(As + (wr * 64 + i * 16 + lr) * 32 + g * 8);
        #pragma unroll
        for (int i = 0; i < 4; i++)
            bf[i] = ld_bf8(Bs + (wc * 64 + i * 16 + lr) * 32 + g * 8);
        #pragma unroll
        for (int i = 0; i < 4; i++)
            #pragma unroll
            for (int n = 0; n < 4; n++)
                acc[i][n] = __builtin_amdgcn_mfma_f32_16x16x32_bf16(af[i], bf[n], acc[i][n], 0, 0, 0);
    }
    #pragma unroll
    for (int i = 0; i < 4; i++)
        #pragma unroll
        for (int n = 0; n < 4; n++)
            #pragma unroll
            for (int r = 0; r < 4; r++) {
                int row = m0 + wr * 64 + i * 16 + g * 4 + r;
                int col = n0 + wc * 64 + n * 16 + lr;
                float v = acc[i][n][r];
                if constexpr (sizeof(OUT_T) == 2) C[(size_t)row * N + col] = f2bf(v);
                else                              C[(size_t)row * N + col] = v;
            }
}

// ---------------- causal GQA flash attention ----------------
// Qb [S][4096] (rope'd), Kb = KVb [S][2048] cols 0..1023 (rope'd), VbT [1024][2048], Ab [S][4096]
__global__ __launch_bounds__(256)
void k_attn(const u16* __restrict__ Qb, const u16* __restrict__ Kb,
            const u16* __restrict__ VbT, u16* __restrict__ Ab) {
    __shared__ __align__(16) u16 Ks[64 * 128];   // [kv][d] swizzled
    __shared__ __align__(16) u16 Vts[128 * 64];  // [d][kv] swizzled
    __shared__ __align__(16) u16 Ps[4][16][72];  // per-wave P scratch, padded rows

    const int qt = blockIdx.x, h = blockIdx.y;
    const int hk = h >> 2;
    const int q0 = qt * 64;
    const int tid = threadIdx.x, lane = tid & 63, wid = tid >> 6;
    const int g = lane >> 4, lr = lane & 15;
    const float scale = 0.08838834764831845f;  // 1/sqrt(128)

    bf16x8 qf[4];
    {
        const u16* qrow = Qb + (size_t)(q0 + wid * 16 + lr) * (NHEADS * DHEAD) + h * DHEAD;
        #pragma unroll
        for (int c = 0; c < 4; c++) qf[c] = ld_bf8(qrow + c * 32 + g * 8);
    }
    float m[4]    = {-1e30f, -1e30f, -1e30f, -1e30f};
    float lsum[4] = {0.f, 0.f, 0.f, 0.f};
    f32x4 acc[8] = {};

    const int nkt = qt + 1;
    for (int kt = 0; kt < nkt; kt++) {
        const int k0 = kt * 64;
        __syncthreads();
        // stage K tile [64][128]
        #pragma unroll
        for (int j = 0; j < 4; j++) {
            int c = tid + j * 256;
            int row = c >> 4, co = (c & 15) << 4;
            int4 v = *(const int4*)(Kb + (size_t)(k0 + row) * 2048 + hk * DHEAD + (co >> 1));
            *(int4*)((char*)Ks + row * 256 + (co ^ ((row & 7) << 4))) = v;
        }
        // stage Vt tile [128][64]
        #pragma unroll
        for (int j = 0; j < 4; j++) {
            int c = tid + j * 256;
            int row = c >> 3, co = (c & 7) << 4;
            int4 v = *(const int4*)(VbT + (size_t)(hk * DHEAD + row) * S_LEN + k0 + (co >> 1));
            *(int4*)((char*)Vts + row * 128 + (co ^ ((row & 7) << 4))) = v;
        }
        __syncthreads();

        // scores: 16x64 per wave
        f32x4 sf[4];
        #pragma unroll
        for (int st = 0; st < 4; st++) {
            f32x4 s = {0.f, 0.f, 0.f, 0.f};
            #pragma unroll
            for (int c = 0; c < 4; c++) {
                int row = st * 16 + lr;
                int cb = (c * 32 + g * 8) * 2;
                bf16x8 kf = ld_bf8((const char*)Ks + row * 256 + (cb ^ ((row & 7) << 4)));
                s = __builtin_amdgcn_mfma_f32_16x16x32_bf16(qf[c], kf, s, 0, 0, 0);
            }
            sf[st] = s;
        }
        if (kt == nkt - 1) {  // diagonal tile: k0 == q0, mask kv>q (local compare valid)
            #pragma unroll
            for (int st = 0; st < 4; st++)
                #pragma unroll
                for (int r = 0; r < 4; r++) {
                    int qg = wid * 16 + g * 4 + r;
                    int kg = st * 16 + lr;
                    sf[st][r] = (kg > qg) ? -1e30f : sf[st][r] * scale;
                }
        } else {
            #pragma unroll
            for (int st = 0; st < 4; st++)
                #pragma unroll
                for (int r = 0; r < 4; r++) sf[st][r] *= scale;
        }
        // online softmax (rows live across the 16 lanes of each g-group)
        float corr[4];
        #pragma unroll
        for (int r = 0; r < 4; r++) {
            float v = fmaxf(fmaxf(sf[0][r], sf[1][r]), fmaxf(sf[2][r], sf[3][r]));
            #pragma unroll
            for (int off = 1; off < 16; off <<= 1) v = fmaxf(v, __shfl_xor(v, off, 64));
            float mn = fmaxf(m[r], v);
            corr[r] = __expf(m[r] - mn);
            m[r] = mn;
        }
        float ts[4] = {0.f, 0.f, 0.f, 0.f};
        #pragma unroll
        for (int st = 0; st < 4; st++)
            #pragma unroll
            for (int r = 0; r < 4; r++) {
                float p = __expf(sf[st][r] - m[r]);
                sf[st][r] = p;
                ts[r] += p;
            }
        #pragma unroll
        for (int r = 0; r < 4; r++) {
            #pragma unroll
            for (int off = 1; off < 16; off <<= 1) ts[r] += __shfl_xor(ts[r], off, 64);
            lsum[r] = lsum[r] * corr[r] + ts[r];
        }
        #pragma unroll
        for (int n = 0; n < 8; n++)
            #pragma unroll
            for (int r = 0; r < 4; r++) acc[n][r] *= corr[r];

        // P -> wave-private LDS (C-layout write, A-layout read)
        #pragma unroll
        for (int st = 0; st < 4; st++)
            #pragma unroll
            for (int r = 0; r < 4; r++)
                Ps[wid][g * 4 + r][st * 16 + lr] = f2bf(sf[st][r]);
        asm volatile("s_waitcnt lgkmcnt(0)" ::: "memory");
        // PV
        #pragma unroll
        for (int c2 = 0; c2 < 2; c2++) {
            bf16x8 pa = ld_bf8(&Ps[wid][lr][c2 * 32 + g * 8]);
            #pragma unroll
            for (int n = 0; n < 8; n++) {
                int row = n * 16 + lr;
                int cb = (c2 * 32 + g * 8) * 2;
                bf16x8 vf = ld_bf8((const char*)Vts + row * 128 + (cb ^ ((row & 7) << 4)));
                acc[n] = __builtin_amdgcn_mfma_f32_16x16x32_bf16(pa, vf, acc[n], 0, 0, 0);
            }
        }
    }
    #pragma unroll
    for (int n = 0; n < 8; n++)
        #pragma unroll
        for (int r = 0; r < 4; r++) {
            int row = q0 + wid * 16 + g * 4 + r;
            int col = h * DHEAD + n * 16 + lr;
            Ab[(size_t)row * (NHEADS * DHEAD) + col] = f2bf(acc[n][r] / lsum[r]);
        }
}

extern "C" void kernel_launch(void* const* d_in, const int* in_sizes, int n_in,
                              void* d_out, int out_size, void* d_ws, size_t ws_size,
                              hipStream_t stream) {
    const float* hidden = (const float*)d_in[0];
    const float* cosT   = (const float*)d_in[1];
    const float* sinT   = (const float*)d_in[2];
    // d_in[3] attention_mask: known causal, implemented directly
    const float* Wq = (const float*)d_in[4];
    const float* Wk = (const float*)d_in[5];
    const float* Wv = (const float*)d_in[6];
    const float* Wo = (const float*)d_in[7];
    float* out = (float*)d_out;
    char* ws = (char*)d_ws;

    // workspace layout (bf16 buffers), 124 MB total; Ab aliases Xbf (dead by then)
    u16* Xbf  = (u16*)(ws);                         // [2048][4096]  16MB
    u16* WqT  = (u16*)(ws + (16u << 20));           // [4096][4096]  32MB
    u16* WkvT = (u16*)(ws + (48u << 20));           // [2048][4096]  16MB (WkT then WvT)
    u16* WoT  = (u16*)(ws + (64u << 20));           // [4096][4096]  32MB
    u16* Qb   = (u16*)(ws + (96u << 20));           // [2048][4096]  16MB
    u16* KVb  = (u16*)(ws + (112u << 20));          // [2048][2048]   8MB (K | V)
    u16* VbT  = (u16*)(ws + (120u << 20));          // [1024][2048]   4MB
    u16* Ab   = Xbf;                                // [2048][4096]  (alias)

    k_cvt<<<dim3((S_LEN * DMODEL / 8) / 256), 256, 0, stream>>>(hidden, Xbf, S_LEN * DMODEL / 8);
    k_transpose_bf16<float><<<dim3(4096 / 32, 4096 / 32), 256, 0, stream>>>(Wq, WqT, 4096, 4096, 4096);
    k_transpose_bf16<float><<<dim3(1024 / 32, 4096 / 32), 256, 0, stream>>>(Wk, WkvT, 4096, 1024, 1024);
    k_transpose_bf16<float><<<dim3(1024 / 32, 4096 / 32), 256, 0, stream>>>(Wv, WkvT + (size_t)1024 * 4096, 4096, 1024, 1024);
    k_transpose_bf16<float><<<dim3(4096 / 32, 4096 / 32), 256, 0, stream>>>(Wo, WoT, 4096, 4096, 4096);

    // projections
    k_gemm_bt<u16><<<dim3(4096 / 128, 2048 / 128), 256, 0, stream>>>(Xbf, WqT,  Qb,  2048, 4096, 4096);
    k_gemm_bt<u16><<<dim3(2048 / 128, 2048 / 128), 256, 0, stream>>>(Xbf, WkvT, KVb, 2048, 2048, 4096);

    // RoPE on Q and K
    k_rope<<<(2048 * 32 * 64) / 256, 256, 0, stream>>>(Qb, cosT, sinT, 32, 4096);
    k_rope<<<(2048 * 8 * 64) / 256, 256, 0, stream>>>(KVb, cosT, sinT, 8, 2048);

    // V^T for PV contiguity
    k_transpose_bf16<u16><<<dim3(1024 / 32, 2048 / 32), 256, 0, stream>>>(KVb + 1024, VbT, 2048, 1024, 2048);

    // attention
    k_attn<<<dim3(32, 32), 256, 0, stream>>>(Qb, KVb, VbT, Ab);

    // output projection (fp32 out)
    k_gemm_bt<float><<<dim3(4096 / 128, 2048 / 128), 256, 0, stream>>>(Ab, WoT, out, 2048, 4096, 4096);
}

// Round 2
// 411.598 us; speedup vs baseline: 1.3256x; 1.3256x over previous
//
#include <hip/hip_runtime.h>
#include <hip/hip_bf16.h>
#include <stdint.h>

typedef unsigned short u16;
typedef unsigned int u32;
typedef __bf16 bf16x8 __attribute__((ext_vector_type(8)));
typedef float f32x4 __attribute__((ext_vector_type(4)));
typedef u16 u16x8 __attribute__((ext_vector_type(8)));

#define S_LEN 2048
#define DMODEL 4096
#define NHEADS 32
#define NKVH 8
#define DHEAD 128
#define LDQK 6144   // row stride of fused QKV activation buffer

__device__ __forceinline__ float bf2f(u16 x) {
    union { u32 i; float f; } u; u.i = ((u32)x) << 16; return u.f;
}
__device__ __forceinline__ u16 f2bf(float f) {
    union { float f; u32 i; } u; u.f = f;
    u32 x = u.i;
    return (u16)((x + 0x7fffu + ((x >> 16) & 1u)) >> 16);
}
__device__ __forceinline__ bf16x8 ld_bf8(const void* p) {
    int4 v = *(const int4*)p;
    return __builtin_bit_cast(bf16x8, v);
}

// ---------------- fp32 -> bf16 elementwise ----------------
__global__ void k_cvt(const float* __restrict__ in, u16* __restrict__ out, int n8) {
    int i = blockIdx.x * 256 + threadIdx.x;
    if (i >= n8) return;
    const float4* p = (const float4*)in + (size_t)i * 2;
    float4 a = p[0], b = p[1];
    u16x8 o;
    o[0]=f2bf(a.x); o[1]=f2bf(a.y); o[2]=f2bf(a.z); o[3]=f2bf(a.w);
    o[4]=f2bf(b.x); o[5]=f2bf(b.y); o[6]=f2bf(b.z); o[7]=f2bf(b.w);
    *((u16x8*)out + i) = o;
}

// ---------------- transpose (+convert) to bf16: in[R][C] (ldin) -> out[C][R] ----------------
template<typename TIN>
__global__ void k_transpose_bf16(const TIN* __restrict__ in, u16* __restrict__ out,
                                 int R, int C, int ldin) {
    __shared__ u16 tile[32][33];
    int c0 = blockIdx.x * 32, r0 = blockIdx.y * 32;
    int tx = threadIdx.x & 31, ty = threadIdx.x >> 5;
    #pragma unroll
    for (int i = 0; i < 4; i++) {
        int r = ty + i * 8;
        TIN v = in[(size_t)(r0 + r) * ldin + c0 + tx];
        if constexpr (sizeof(TIN) == 4) tile[r][tx] = f2bf((float)v);
        else tile[r][tx] = (u16)v;
    }
    __syncthreads();
    #pragma unroll
    for (int i = 0; i < 4; i++) {
        int r = ty + i * 8;
        out[(size_t)(c0 + r) * R + r0 + tx] = tile[tx][r];
    }
}

// ---------------- RoPE in place on [S][nh*128] bf16 (row stride ld) ----------------
__global__ void k_rope(u16* __restrict__ X, const float* __restrict__ cosT,
                       const float* __restrict__ sinT, int nh, int ld) {
    int idx = blockIdx.x * 256 + threadIdx.x;
    int d = idx & 63;
    int h = (idx >> 6) % nh;
    int s = idx / (64 * nh);
    u16* p = X + (size_t)s * ld + h * DHEAD;
    float x1 = bf2f(p[d]), x2 = bf2f(p[d + 64]);
    float c1 = cosT[s * DHEAD + d],      s1 = sinT[s * DHEAD + d];
    float c2 = cosT[s * DHEAD + d + 64], s2 = sinT[s * DHEAD + d + 64];
    p[d]      = f2bf(x1 * c1 - x2 * s1);
    p[d + 64] = f2bf(x2 * c2 + x1 * s2);
}

// ---------------- m97-structure bt-GEMM: C[M][N] = A[M][K] * Bt[N][K]^T ----------------
typedef const __attribute__((address_space(1))) u32 GBUF;
typedef __attribute__((address_space(3))) u32 LBUF;

template<typename OUT_T>
__global__ __launch_bounds__(256)
void k_gemm_bt(const u16* __restrict__ A, const u16* __restrict__ Bt,
               OUT_T* __restrict__ C, int M, int N, int K) {
    __shared__ __align__(16) u16 As[128 * 32];
    __shared__ __align__(16) u16 Bs[128 * 32];
    const int m0 = blockIdx.y * 128, n0 = blockIdx.x * 128;
    const int tid = threadIdx.x, lane = tid & 63, wid = tid >> 6;
    const int wr = wid >> 1, wc = wid & 1;
    const int g = lane >> 4, lr = lane & 15;

    f32x4 acc[4][4] = {};

    for (int k0 = 0; k0 < K; k0 += 32) {
        __syncthreads();
        #pragma unroll
        for (int j = 0; j < 2; j++) {
            int c = wid * 128 + j * 64 + lane;     // chunk 0..511 (16B each)
            int r = c >> 2, co = (c & 3) << 3;     // row 0..127, col offset {0,8,16,24}
            __builtin_amdgcn_global_load_lds((GBUF*)(A  + (size_t)(m0 + r) * K + k0 + co),
                                             (LBUF*)(As + (size_t)(wid * 128 + j * 64) * 8), 16, 0, 0);
            __builtin_amdgcn_global_load_lds((GBUF*)(Bt + (size_t)(n0 + r) * K + k0 + co),
                                             (LBUF*)(Bs + (size_t)(wid * 128 + j * 64) * 8), 16, 0, 0);
        }
        __syncthreads();
        bf16x8 af[4], bf[4];
        #pragma unroll
        for (int i = 0; i < 4; i++)
            af[i] = ld_bf8(As + (wr * 64 + i * 16 + lr) * 32 + g * 8);
        #pragma unroll
        for (int i = 0; i < 4; i++)
            bf[i] = ld_bf8(Bs + (wc * 64 + i * 16 + lr) * 32 + g * 8);
        #pragma unroll
        for (int i = 0; i < 4; i++)
            #pragma unroll
            for (int n = 0; n < 4; n++)
                acc[i][n] = __builtin_amdgcn_mfma_f32_16x16x32_bf16(af[i], bf[n], acc[i][n], 0, 0, 0);
    }
    #pragma unroll
    for (int i = 0; i < 4; i++)
        #pragma unroll
        for (int n = 0; n < 4; n++)
            #pragma unroll
            for (int r = 0; r < 4; r++) {
                int row = m0 + wr * 64 + i * 16 + g * 4 + r;
                int col = n0 + wc * 64 + n * 16 + lr;
                float v = acc[i][n][r];
                if constexpr (sizeof(OUT_T) == 2) C[(size_t)row * N + col] = f2bf(v);
                else                              C[(size_t)row * N + col] = v;
            }
}

// ---------------- causal GQA flash attention, 2-phase pipelined ----------------
// Each block: q-tile pair (p, 31-p) for one head -> constant 33 kv-tile iterations.
// K/V double-buffered in dynamic LDS, staged via global_load_lds with
// pre-swizzled SOURCE address (linear LDS dest), single barrier per iteration.
// LDS layout: Ks[2][64*128]u16 @0, Vts[2][128*64]u16 @32768, Ps[4][16][72]u16 @65536
__global__ __launch_bounds__(256)
void k_attn2(const u16* __restrict__ Qb, const u16* __restrict__ Kb,
             const u16* __restrict__ VbT, u16* __restrict__ Ab) {
    extern __shared__ __align__(16) char smem[];

    const int p = blockIdx.x, h = blockIdx.y, hk = h >> 2;
    const int tid = threadIdx.x, lane = tid & 63, wid = tid >> 6;
    const int g = lane >> 4, lr = lane & 15;
    const float scale = 0.08838834764831845f;  // 1/sqrt(128)
    const int qtA = p, qtB = 31 - p, nA = qtA + 1;
    const int NIT = 33;

    const int krow_l = lane >> 4, kc16 = lane & 15;   // K-stage lane decomposition
    const int vrow_l = lane >> 3, vc8  = lane & 7;    // V-stage lane decomposition

    u16* PsB = (u16*)(smem + 65536) + wid * 16 * 72;

    // stage one 64-kv tile (K: [64][128], Vt: [128][64]) into buffer `buf`
    auto stage = [&](int buf, int k0) {
        u16* KsD = (u16*)smem + buf * 8192;
        u16* VtD = (u16*)(smem + 32768) + buf * 8192;
        #pragma unroll
        for (int j = 0; j < 4; j++) {
            int rowt = wid * 16 + j * 4 + krow_l;           // 0..63
            int c16  = kc16 ^ (rowt & 7);                   // pre-swizzled source col (16B units)
            __builtin_amdgcn_global_load_lds(
                (GBUF*)(Kb + (size_t)(k0 + rowt) * LDQK + hk * DHEAD + c16 * 8),
                (LBUF*)(KsD + (wid * 16 + j * 4) * 128), 16, 0, 0);
        }
        #pragma unroll
        for (int j = 0; j < 4; j++) {
            int rowt = wid * 32 + j * 8 + vrow_l;           // 0..127
            int c8   = vc8 ^ (rowt & 7);
            __builtin_amdgcn_global_load_lds(
                (GBUF*)(VbT + (size_t)(hk * DHEAD + rowt) * S_LEN + k0 + c8 * 8),
                (LBUF*)(VtD + (wid * 32 + j * 8) * 64), 16, 0, 0);
        }
    };

    bf16x8 qf[4];
    f32x4 acc[8];
    float m[4], lsum[4];
    int qt = qtA, q0 = qtA * 64;

    stage(0, 0);
    asm volatile("s_waitcnt vmcnt(0)" ::: "memory");
    __builtin_amdgcn_s_barrier();

    for (int i = 0; i < NIT; i++) {
        const int kt = (i < nA) ? i : (i - nA);
        // issue next tile's loads (other buffer) before computing current
        if (i + 1 < NIT) {
            int kt1 = (i + 1 < nA) ? (i + 1) : (i + 1 - nA);
            stage((i + 1) & 1, kt1 * 64);
        }
        // q-tile boundary: flush previous output, load new Q frags, reset state
        if (i == 0 || i == nA) {
            if (i == nA) {
                #pragma unroll
                for (int n = 0; n < 8; n++)
                    #pragma unroll
                    for (int r = 0; r < 4; r++)
                        Ab[(size_t)(q0 + wid * 16 + g * 4 + r) * DMODEL + h * DHEAD + n * 16 + lr]
                            = f2bf(acc[n][r] / lsum[r]);
            }
            qt = (i == 0) ? qtA : qtB;
            q0 = qt * 64;
            const u16* qrow = Qb + (size_t)(q0 + wid * 16 + lr) * LDQK + h * DHEAD;
            #pragma unroll
            for (int c = 0; c < 4; c++) qf[c] = ld_bf8(qrow + c * 32 + g * 8);
            #pragma unroll
            for (int n = 0; n < 8; n++) acc[n] = (f32x4){0.f, 0.f, 0.f, 0.f};
            #pragma unroll
            for (int r = 0; r < 4; r++) { m[r] = -1e30f; lsum[r] = 0.f; }
        }

        const char* KsB = smem + (i & 1) * 16384;
        const char* VtB = smem + 32768 + (i & 1) * 16384;

        // ---- QK^T: 16 q-rows x 64 kv per wave ----
        f32x4 sf[4];
        __builtin_amdgcn_s_setprio(1);
        #pragma unroll
        for (int st = 0; st < 4; st++) {
            f32x4 s = {0.f, 0.f, 0.f, 0.f};
            #pragma unroll
            for (int c = 0; c < 4; c++) {
                int row = st * 16 + lr;
                int cb = (c * 32 + g * 8) * 2;
                bf16x8 kf = ld_bf8(KsB + row * 256 + (cb ^ ((row & 7) << 4)));
                s = __builtin_amdgcn_mfma_f32_16x16x32_bf16(qf[c], kf, s, 0, 0, 0);
            }
            sf[st] = s;
        }
        __builtin_amdgcn_s_setprio(0);

        if (kt == qt) {  // diagonal tile: mask kv>q
            #pragma unroll
            for (int st = 0; st < 4; st++)
                #pragma unroll
                for (int r = 0; r < 4; r++) {
                    int qg = wid * 16 + g * 4 + r;
                    int kg = st * 16 + lr;
                    sf[st][r] = (kg > qg) ? -1e30f : sf[st][r] * scale;
                }
        } else {
            #pragma unroll
            for (int st = 0; st < 4; st++)
                #pragma unroll
                for (int r = 0; r < 4; r++) sf[st][r] *= scale;
        }

        // ---- online softmax (rows live across 16 lanes of each g-group) ----
        float corr[4];
        #pragma unroll
        for (int r = 0; r < 4; r++) {
            float v = fmaxf(fmaxf(sf[0][r], sf[1][r]), fmaxf(sf[2][r], sf[3][r]));
            #pragma unroll
            for (int off = 1; off < 16; off <<= 1) v = fmaxf(v, __shfl_xor(v, off, 64));
            float mn = fmaxf(m[r], v);
            corr[r] = __expf(m[r] - mn);
            m[r] = mn;
        }
        float ts[4] = {0.f, 0.f, 0.f, 0.f};
        #pragma unroll
        for (int st = 0; st < 4; st++)
            #pragma unroll
            for (int r = 0; r < 4; r++) {
                float pv = __expf(sf[st][r] - m[r]);
                sf[st][r] = pv;
                ts[r] += pv;
            }
        #pragma unroll
        for (int r = 0; r < 4; r++) {
            #pragma unroll
            for (int off = 1; off < 16; off <<= 1) ts[r] += __shfl_xor(ts[r], off, 64);
            lsum[r] = lsum[r] * corr[r] + ts[r];
        }
        #pragma unroll
        for (int n = 0; n < 8; n++)
            #pragma unroll
            for (int r = 0; r < 4; r++) acc[n][r] *= corr[r];

        // ---- P -> wave-private LDS (C-layout write, A-layout read) ----
        #pragma unroll
        for (int st = 0; st < 4; st++)
            #pragma unroll
            for (int r = 0; r < 4; r++)
                PsB[(g * 4 + r) * 72 + st * 16 + lr] = f2bf(sf[st][r]);
        asm volatile("s_waitcnt lgkmcnt(0)" ::: "memory");

        // ---- PV ----
        __builtin_amdgcn_s_setprio(1);
        #pragma unroll
        for (int c2 = 0; c2 < 2; c2++) {
            bf16x8 pa = ld_bf8(PsB + lr * 72 + c2 * 32 + g * 8);
            #pragma unroll
            for (int n = 0; n < 8; n++) {
                int row = n * 16 + lr;
                int cb = (c2 * 32 + g * 8) * 2;
                bf16x8 vf = ld_bf8(VtB + row * 128 + (cb ^ ((row & 7) << 4)));
                acc[n] = __builtin_amdgcn_mfma_f32_16x16x32_bf16(pa, vf, acc[n], 0, 0, 0);
            }
        }
        __builtin_amdgcn_s_setprio(0);

        // ---- end of iteration: reads of cur buf done + next stage landed ----
        asm volatile("s_waitcnt lgkmcnt(0)" ::: "memory");
        __builtin_amdgcn_sched_barrier(0);
        asm volatile("s_waitcnt vmcnt(0)" ::: "memory");
        __builtin_amdgcn_s_barrier();
    }

    // flush segment B
    #pragma unroll
    for (int n = 0; n < 8; n++)
        #pragma unroll
        for (int r = 0; r < 4; r++)
            Ab[(size_t)(q0 + wid * 16 + g * 4 + r) * DMODEL + h * DHEAD + n * 16 + lr]
                = f2bf(acc[n][r] / lsum[r]);
}

extern "C" void kernel_launch(void* const* d_in, const int* in_sizes, int n_in,
                              void* d_out, int out_size, void* d_ws, size_t ws_size,
                              hipStream_t stream) {
    const float* hidden = (const float*)d_in[0];
    const float* cosT   = (const float*)d_in[1];
    const float* sinT   = (const float*)d_in[2];
    // d_in[3] attention_mask: known causal, implemented directly
    const float* Wq = (const float*)d_in[4];
    const float* Wk = (const float*)d_in[5];
    const float* Wv = (const float*)d_in[6];
    const float* Wo = (const float*)d_in[7];
    float* out = (float*)d_out;
    char* ws = (char*)d_ws;

    // workspace (peak 120 MB):
    //   [0,16)    Xbf [2048][4096] bf16; later reused as Ab
    //   [16,64)   WqkvT [6144][4096] bf16 (dead after QKV GEMM); VbT aliases its head after
    //   [64,96)   WoT [4096][4096] bf16
    //   [96,120)  QKVb [2048][6144] bf16
    u16* Xbf   = (u16*)ws;
    u16* WqkvT = (u16*)(ws + (16u << 20));
    u16* VbT   = (u16*)(ws + (16u << 20));          // alias: valid after QKV GEMM
    u16* WoT   = (u16*)(ws + (64u << 20));
    u16* QKVb  = (u16*)(ws + (96u << 20));
    u16* Ab    = Xbf;

    k_cvt<<<dim3((S_LEN * DMODEL / 8) / 256), 256, 0, stream>>>(hidden, Xbf, S_LEN * DMODEL / 8);
    k_transpose_bf16<float><<<dim3(4096 / 32, 4096 / 32), 256, 0, stream>>>(Wq, WqkvT, 4096, 4096, 4096);
    k_transpose_bf16<float><<<dim3(1024 / 32, 4096 / 32), 256, 0, stream>>>(Wk, WqkvT + (size_t)4096 * 4096, 4096, 1024, 1024);
    k_transpose_bf16<float><<<dim3(1024 / 32, 4096 / 32), 256, 0, stream>>>(Wv, WqkvT + (size_t)5120 * 4096, 4096, 1024, 1024);
    k_transpose_bf16<float><<<dim3(4096 / 32, 4096 / 32), 256, 0, stream>>>(Wo, WoT, 4096, 4096, 4096);

    // fused QKV projection: [2048][4096] x [6144][4096]^T -> [2048][6144]
    k_gemm_bt<u16><<<dim3(6144 / 128, 2048 / 128), 256, 0, stream>>>(Xbf, WqkvT, QKVb, 2048, 6144, 4096);

    // RoPE on Q (cols 0..4095) and K (cols 4096..5119)
    k_rope<<<(2048 * 32 * 64) / 256, 256, 0, stream>>>(QKVb, cosT, sinT, 32, LDQK);
    k_rope<<<(2048 * 8 * 64) / 256, 256, 0, stream>>>(QKVb + 4096, cosT, sinT, 8, LDQK);

    // V^T (cols 5120..6143 of QKVb) -> VbT [1024][2048]
    k_transpose_bf16<u16><<<dim3(1024 / 32, 2048 / 32), 256, 0, stream>>>(QKVb + 5120, VbT, 2048, 1024, LDQK);

    // attention: 16 q-tile pairs x 32 heads, 74752 B dynamic LDS
    hipFuncSetAttribute((const void*)k_attn2, hipFuncAttributeMaxDynamicSharedMemorySize, 74752);
    k_attn2<<<dim3(16, 32), 256, 74752, stream>>>(QKVb, QKVb + 4096, VbT, Ab);

    // output projection (fp32 out)
    k_gemm_bt<float><<<dim3(4096 / 128, 2048 / 128), 256, 0, stream>>>(Ab, WoT, out, 2048, 4096, 4096);
}